// Round 1
// baseline (343.278 us; speedup 1.0000x reference)
//
#include <hip/hip_runtime.h>

// x: (64, 256, 56, 56) fp32.  Channel-block n:m sparsity:
//   mask1: keep top-2 of every 4 channels (ties kept, >= 2nd-largest |x|)
//   mask2: on residual (kept entries zeroed), keep top-1 of every 8 channels
//   out = x * (mask1 | mask2)
// One thread = 4 spatial positions (float4) x 8 channels (one m2 block).

#define N_IMG   64
#define C_CH    256
#define HW      3136          // 56*56
#define HW4     784           // HW / 4
#define CH_OCT  32            // C / 8

__device__ __forceinline__ float second_largest4(float a, float b, float c, float d) {
    float mab = fmaxf(a, b), nab = fminf(a, b);
    float mcd = fmaxf(c, d), ncd = fminf(c, d);
    return fmaxf(fminf(mab, mcd), fmaxf(nab, ncd));
}

__global__ __launch_bounds__(256) void sparsity_kernel(const float* __restrict__ x,
                                                       float* __restrict__ out) {
    const int idx = blockIdx.x * 256 + threadIdx.x;   // over n*hw4 = 50176 (exact)
    const int cb  = blockIdx.y;                        // channel octet 0..31
    const int n   = idx / HW4;
    const int hw4 = idx - n * HW4;

    const size_t base = (size_t)n * (C_CH * HW) + (size_t)cb * (8 * HW) + (size_t)hw4 * 4;
    const float4* __restrict__ px = (const float4*)(x + base);
    float4* __restrict__ po = (float4*)(out + base);

    // Load 8 channels x 4 spatial (each load coalesced across the wave)
    float v[8][4];
    #pragma unroll
    for (int c = 0; c < 8; ++c) {
        float4 t = px[c * (HW / 4)];
        v[c][0] = t.x; v[c][1] = t.y; v[c][2] = t.z; v[c][3] = t.w;
    }

    float o[8][4];
    #pragma unroll
    for (int e = 0; e < 4; ++e) {
        float a[8];
        #pragma unroll
        for (int c = 0; c < 8; ++c) a[c] = fabsf(v[c][e]);

        const float thr1a = second_largest4(a[0], a[1], a[2], a[3]);
        const float thr1b = second_largest4(a[4], a[5], a[6], a[7]);

        bool  m1[8];
        float res[8];
        #pragma unroll
        for (int c = 0; c < 4; ++c) { m1[c] = a[c] >= thr1a; res[c] = m1[c] ? 0.0f : a[c]; }
        #pragma unroll
        for (int c = 4; c < 8; ++c) { m1[c] = a[c] >= thr1b; res[c] = m1[c] ? 0.0f : a[c]; }

        float thr2 = res[0];
        #pragma unroll
        for (int c = 1; c < 8; ++c) thr2 = fmaxf(thr2, res[c]);

        #pragma unroll
        for (int c = 0; c < 8; ++c) {
            const bool keep = m1[c] | (res[c] >= thr2);
            o[c][e] = keep ? v[c][e] : 0.0f;
        }
    }

    #pragma unroll
    for (int c = 0; c < 8; ++c) {
        float4 t;
        t.x = o[c][0]; t.y = o[c][1]; t.z = o[c][2]; t.w = o[c][3];
        po[c * (HW / 4)] = t;
    }
}

extern "C" void kernel_launch(void* const* d_in, const int* in_sizes, int n_in,
                              void* d_out, int out_size, void* d_ws, size_t ws_size,
                              hipStream_t stream) {
    const float* x = (const float*)d_in[0];
    float* out = (float*)d_out;
    dim3 grid((N_IMG * HW4) / 256, CH_OCT);  // 196 x 32 = 6272 blocks
    sparsity_kernel<<<grid, 256, 0, stream>>>(x, out);
}

// Round 3
// 329.432 us; speedup vs baseline: 1.0420x; 1.0420x over previous
//
#include <hip/hip_runtime.h>

// x: (64, 256, 56, 56) fp32.  Channel-block n:m sparsity:
//   mask1: keep top-2 of every 4 channels (ties kept, >= 2nd-largest |x|)
//   mask2: on residual (kept entries zeroed), keep top-1 of every 8 channels
//   out = x * (mask1 | mask2)
// One thread = 4 spatial positions (float4) x 8 channels (one m2 block).
// R2: mask in place (halve live VGPRs -> more waves for latency hiding),
//     nontemporal load/store (streaming, zero reuse, skip cache pollution).
// R3: use clang ext_vector_type float4 — __builtin_nontemporal_* rejects
//     HIP_vector_type structs.

#define N_IMG   64
#define C_CH    256
#define HW      3136          // 56*56
#define HW4     784           // HW / 4
#define CH_OCT  32            // C / 8

typedef float vfloat4 __attribute__((ext_vector_type(4)));

__device__ __forceinline__ float second_largest4(float a, float b, float c, float d) {
    float mab = fmaxf(a, b), nab = fminf(a, b);
    float mcd = fmaxf(c, d), ncd = fminf(c, d);
    return fmaxf(fminf(mab, mcd), fmaxf(nab, ncd));
}

__global__ __launch_bounds__(256) void sparsity_kernel(const float* __restrict__ x,
                                                       float* __restrict__ out) {
    const int idx = blockIdx.x * 256 + threadIdx.x;   // over n*hw4 = 50176 (exact)
    const int cb  = blockIdx.y;                        // channel octet 0..31
    const int n   = idx / HW4;
    const int hw4 = idx - n * HW4;

    const size_t base = (size_t)n * (C_CH * HW) + (size_t)cb * (8 * HW) + (size_t)hw4 * 4;
    const vfloat4* __restrict__ px = (const vfloat4*)(x + base);
    vfloat4* __restrict__ po = (vfloat4*)(out + base);

    // Load 8 channels x 4 spatial (each load coalesced across the wave)
    vfloat4 v[8];
    #pragma unroll
    for (int c = 0; c < 8; ++c) {
        v[c] = __builtin_nontemporal_load(&px[c * (HW / 4)]);
    }

    // Mask in place, one spatial element at a time (keeps temporaries small).
    #pragma unroll
    for (int e = 0; e < 4; ++e) {
        float a[8];
        #pragma unroll
        for (int c = 0; c < 8; ++c) a[c] = fabsf(v[c][e]);

        const float thr1a = second_largest4(a[0], a[1], a[2], a[3]);
        const float thr1b = second_largest4(a[4], a[5], a[6], a[7]);

        float res[8];
        bool  m1[8];
        #pragma unroll
        for (int c = 0; c < 4; ++c) { m1[c] = a[c] >= thr1a; res[c] = m1[c] ? 0.0f : a[c]; }
        #pragma unroll
        for (int c = 4; c < 8; ++c) { m1[c] = a[c] >= thr1b; res[c] = m1[c] ? 0.0f : a[c]; }

        float thr2 = res[0];
        #pragma unroll
        for (int c = 1; c < 8; ++c) thr2 = fmaxf(thr2, res[c]);

        #pragma unroll
        for (int c = 0; c < 8; ++c) {
            const bool keep = m1[c] | (res[c] >= thr2);
            v[c][e] = keep ? v[c][e] : 0.0f;
        }
    }

    #pragma unroll
    for (int c = 0; c < 8; ++c) {
        __builtin_nontemporal_store(v[c], &po[c * (HW / 4)]);
    }
}

extern "C" void kernel_launch(void* const* d_in, const int* in_sizes, int n_in,
                              void* d_out, int out_size, void* d_ws, size_t ws_size,
                              hipStream_t stream) {
    const float* x = (const float*)d_in[0];
    float* out = (float*)d_out;
    dim3 grid((N_IMG * HW4) / 256, CH_OCT);  // 196 x 32 = 6272 blocks
    sparsity_kernel<<<grid, 256, 0, stream>>>(x, out);
}